// Round 2
// baseline (1288.682 us; speedup 1.0000x reference)
//
#include <hip/hip_runtime.h>

typedef unsigned short ushort_t;
typedef unsigned int u32;
typedef float f32x4 __attribute__((ext_vector_type(4)));
typedef __bf16 bf16x8 __attribute__((ext_vector_type(8)));

#define B_ 8
#define L_ 4096
#define D_ 384
#define DI_ 768
#define S_ 16
#define NC_ 40
#define ML_ (B_*L_)   // 32768 rows

// ---------------- workspace layout (bytes) ----------------
// Total ~154 MB (previous 287 MB likely exceeded ws_size -> GPU page fault).
// Aliasing: XN lives in XC's region (dead after gemm1, before conv writes XC);
//           XDBL lives in XP's region (XP dead after conv, before xproj writes XDBL).
constexpr size_t au(size_t x){ return (x + 255) & ~size_t(255); }
constexpr size_t O_FLAG = 0;                                   // int
constexpr size_t O_LNW  = 256;                                 // 384 f32
constexpr size_t O_CONVW= au(O_LNW  + 384*4);                  // 3072 f32
constexpr size_t O_CONVB= au(O_CONVW+ 3072*4);                 // 768 f32
constexpr size_t O_WDT  = au(O_CONVB+ 768*4);                  // 18432 f32
constexpr size_t O_DTB  = au(O_WDT  + 18432*4);                // 768 f32
constexpr size_t O_A    = au(O_DTB  + 768*4);                  // 12288 f32 (A = -exp(A_log))
constexpr size_t O_DSKIP= au(O_A    + 12288*4);                // 768 f32
constexpr size_t O_WOUT = au(O_DSKIP+ 768*4);                  // 294912 f32
constexpr size_t O_WFC  = au(O_WOUT + 294912*4);               // 98304 f32
constexpr size_t O_BFC  = au(O_WFC  + 98304*4);                // 256 f32
constexpr size_t O_GAM  = au(O_BFC  + 256*4);
constexpr size_t O_BET  = au(O_GAM  + 256*4);
constexpr size_t O_WCLS = au(O_BET  + 256*4);                  // 10240 f32
constexpr size_t O_BCLS = au(O_WCLS + 10240*4);                // 40 f32
constexpr size_t O_XMEAN= au(O_BCLS + 40*4);                   // 8*384 f32 (atomic acc, zeroed in prep)
constexpr size_t O_YMEAN= au(O_XMEAN+ 3072*4);                 // 8*768 f32
constexpr size_t O_H    = au(O_YMEAN+ 6144*4);                 // 8*256 f32
constexpr size_t O_WINT = au(O_H    + 2048*4);                 // W_in^T  [1536][384] bf16
constexpr size_t O_WXT  = au(O_WINT + (size_t)589824*2);       // W_xproj^T padded [64][768] bf16
constexpr size_t O_XP   = au(O_WXT  + (size_t)49152*2);        // [32768][768] bf16
constexpr size_t O_XDBL = O_XP;                                // alias: [32768][56] f32 (after conv)
constexpr size_t O_Z    = au(O_XP   + (size_t)ML_*768*2);      // [32768][768] bf16
constexpr size_t O_XCU  = au(O_Z    + (size_t)ML_*768*2);      // union region, 50.3 MB
constexpr size_t O_XN   = O_XCU;                               // [32768][384] bf16 (dead after gemm1)
constexpr size_t O_XC   = O_XCU;                               // [32768][768] bf16
constexpr size_t WS_NEED= O_XCU + (size_t)ML_*768*2;           // ~154 MB

// ---------------- helpers ----------------
__device__ inline float bf2f(ushort_t u){ return __uint_as_float(((u32)u) << 16); }
__device__ inline ushort_t f2bf(float f){
    u32 x = __float_as_uint(f);
    u32 r = (x + 0x7fffu + ((x >> 16) & 1u)) >> 16;   // RNE
    return (ushort_t)r;
}
__device__ inline float ldf(const void* p, long i, int flag){
    return flag ? bf2f(((const ushort_t*)p)[i]) : ((const float*)p)[i];
}
__device__ inline ushort_t ldbf(const void* p, long i, int flag){
    return flag ? ((const ushort_t*)p)[i] : f2bf(((const float*)p)[i]);
}
__device__ inline float sigm(float v){ return 1.f / (1.f + __expf(-v)); }

__device__ inline void gload_lds16(const void* g, void* l){
    __builtin_amdgcn_global_load_lds(
        (const __attribute__((address_space(1))) u32*)g,
        (__attribute__((address_space(3))) u32*)l, 16, 0, 0);
}

struct Ptrs { const void* p[17]; };

// ---------------- k0: dtype detect ----------------
// bf16 storage of N(0,1): |v| < 8.  fp32 storage: half the ushorts are random
// mantissa halves -> as bf16, maxabs >> 1e4 with P ~ 1-1e-33 over 128 samples.
__global__ void k_detect(const void* x, char* ws){
    __shared__ float s[256];
    int tid = threadIdx.x;
    s[tid] = fabsf(bf2f(((const ushort_t*)x)[tid]));
    __syncthreads();
    for (int st = 128; st > 0; st >>= 1){
        if (tid < st) s[tid] = fmaxf(s[tid], s[tid + st]);
        __syncthreads();
    }
    if (tid == 0) *(int*)(ws + O_FLAG) = (s[0] < 1e4f) ? 1 : 0;
}

// ---------------- k1: weight prep (dual-path loads -> fixed internal fmt) ----
#define N_PREP 1082792L
__global__ __launch_bounds__(256) void k_prep(Ptrs ps, char* ws){
    const int flag = *(const int*)(ws + O_FLAG);
    long o = (long)blockIdx.x * 256 + threadIdx.x;
    if (o < 384){ ((float*)(ws+O_LNW))[o]  = ldf(ps.p[1],o,flag); return; }  o -= 384;
    if (o < 3072){ ((float*)(ws+O_CONVW))[o]= ldf(ps.p[3],o,flag); return; } o -= 3072;
    if (o < 768){ ((float*)(ws+O_CONVB))[o]= ldf(ps.p[4],o,flag); return; }  o -= 768;
    if (o < 18432){ ((float*)(ws+O_WDT))[o]= ldf(ps.p[6],o,flag); return; }  o -= 18432;
    if (o < 768){ ((float*)(ws+O_DTB))[o]  = ldf(ps.p[7],o,flag); return; }  o -= 768;
    if (o < 768){ ((float*)(ws+O_DSKIP))[o]= ldf(ps.p[9],o,flag); return; }  o -= 768;
    if (o < 294912){ ((float*)(ws+O_WOUT))[o]= ldf(ps.p[10],o,flag); return; } o -= 294912;
    if (o < 98304){ ((float*)(ws+O_WFC))[o]= ldf(ps.p[11],o,flag); return; } o -= 98304;
    if (o < 256){ ((float*)(ws+O_BFC))[o]  = ldf(ps.p[12],o,flag); return; } o -= 256;
    if (o < 256){ ((float*)(ws+O_GAM))[o]  = ldf(ps.p[13],o,flag); return; } o -= 256;
    if (o < 256){ ((float*)(ws+O_BET))[o]  = ldf(ps.p[14],o,flag); return; } o -= 256;
    if (o < 10240){ ((float*)(ws+O_WCLS))[o]= ldf(ps.p[15],o,flag); return; } o -= 10240;
    if (o < 40){ ((float*)(ws+O_BCLS))[o]  = ldf(ps.p[16],o,flag); return; } o -= 40;
    if (o < 12288){ ((float*)(ws+O_A))[o]  = -__expf(ldf(ps.p[8],o,flag)); return; } o -= 12288;
    if (o < 589824){                     // W_in [384,1536] -> WinT [1536][384]
        long n = o / 384, k = o % 384;
        ((ushort_t*)(ws+O_WINT))[o] = ldbf(ps.p[2], k*1536 + n, flag); return;
    } o -= 589824;
    if (o < 49152){                      // W_xproj [768,56] -> WxT [64][768], zero-pad n>=56
        long n = o / 768, k = o % 768;
        ((ushort_t*)(ws+O_WXT))[o] = (n < 56) ? ldbf(ps.p[5], k*56 + n, flag) : (ushort_t)0;
        return;
    } o -= 49152;
    if (o < 3072){ ((float*)(ws+O_XMEAN))[o] = 0.f; return; }
}

// ---------------- k2: RMSNorm -> xn (bf16) ----------------
__global__ __launch_bounds__(128) void k_rmsnorm(const void* x, char* ws){
    const int flag = *(const int*)(ws + O_FLAG);
    const float* lnw = (const float*)(ws + O_LNW);
    ushort_t* xn = (ushort_t*)(ws + O_XN);
    long row = blockIdx.x;
    int tid = threadIdx.x;
    float v[3];
    if (flag){
        const ushort_t* xb = (const ushort_t*)x;
        #pragma unroll
        for (int c = 0; c < 3; c++) v[c] = bf2f(xb[row*384 + tid + c*128]);
    } else {
        const float* xf = (const float*)x;
        #pragma unroll
        for (int c = 0; c < 3; c++) v[c] = xf[row*384 + tid + c*128];
    }
    __shared__ float red[128];
    red[tid] = v[0]*v[0] + v[1]*v[1] + v[2]*v[2];
    __syncthreads();
    for (int st = 64; st > 0; st >>= 1){
        if (tid < st) red[tid] += red[tid + st];
        __syncthreads();
    }
    float scale = rsqrtf(red[0] * (1.f/384.f) + 1e-5f);
    #pragma unroll
    for (int c = 0; c < 3; c++)
        xn[row*384 + tid + c*128] = f2bf(v[c] * scale * lnw[tid + c*128]);
}

// ---------------- k3: xmean[b,d] = mean_L x ----------------
__global__ __launch_bounds__(256) void k_xmean(const void* x, char* ws){
    const int flag = *(const int*)(ws + O_FLAG);
    float* xmean = (float*)(ws + O_XMEAN);
    int b = blockIdx.x, d0 = blockIdx.y*128, l0 = blockIdx.z*256;
    int tid = threadIdx.x, dl = tid & 127, lh = tid >> 7;
    float acc = 0.f;
    if (flag){
        const ushort_t* xb = (const ushort_t*)x;
        for (int l = l0 + lh; l < l0 + 256; l += 2)
            acc += bf2f(xb[((long)b*L_ + l)*384 + d0 + dl]);
    } else {
        const float* xf = (const float*)x;
        for (int l = l0 + lh; l < l0 + 256; l += 2)
            acc += xf[((long)b*L_ + l)*384 + d0 + dl];
    }
    __shared__ float s[256];
    s[tid] = acc; __syncthreads();
    if (tid < 128)
        atomicAdd(&xmean[b*384 + d0 + dl], (s[tid] + s[tid+128]) * (1.f/L_));
}

// ---------------- k4: GEMM1  xn[32768,384] @ W_in -> xp | z (bf16) ---------
// m97 structure: 128x128 tile, BK=32, global_load_lds w=16, 2-barrier K-loop.
__global__ __launch_bounds__(256) void k_gemm1(char* ws){
    const ushort_t* xn = (const ushort_t*)(ws + O_XN);
    const ushort_t* wT = (const ushort_t*)(ws + O_WINT);
    ushort_t* xp = (ushort_t*)(ws + O_XP);
    ushort_t* zz = (ushort_t*)(ws + O_Z);
    __shared__ ushort_t sA[128*32];
    __shared__ ushort_t sB[128*32];
    int tid = threadIdx.x, w = tid >> 6, l = tid & 63;
    long m0 = (long)blockIdx.x * 128;
    int n0 = blockIdx.y * 128;
    f32x4 acc[4][4] = {};
    int lr = l >> 2, lk = (l & 3) * 8;
    const ushort_t* gA = xn + (m0 + w*16 + lr)*384 + lk;
    const ushort_t* gB = wT + ((long)(n0 + w*16 + lr))*384 + lk;
    ushort_t* lA = &sA[w*16*32];
    ushort_t* lB = &sB[w*16*32];
    int wm = w & 1, wn = w >> 1;
    int arow = wm*64 + (l & 15);
    int brow = wn*64 + (l & 15);
    int koff = (l >> 4) * 8;
    for (int kc = 0; kc < 12; kc++){
        int k0 = kc * 32;
        gload_lds16(gA + k0,           lA);
        gload_lds16(gA + k0 + 64*384,  lA + 64*32);
        gload_lds16(gB + k0,           lB);
        gload_lds16(gB + k0 + 64*384,  lB + 64*32);
        __syncthreads();
        bf16x8 af[4], bfv[4];
        #pragma unroll
        for (int i = 0; i < 4; i++){
            af[i]  = *(const bf16x8*)&sA[(arow + i*16)*32 + koff];
            bfv[i] = *(const bf16x8*)&sB[(brow + i*16)*32 + koff];
        }
        #pragma unroll
        for (int mb = 0; mb < 4; mb++)
            #pragma unroll
            for (int nb = 0; nb < 4; nb++)
                acc[mb][nb] = __builtin_amdgcn_mfma_f32_16x16x32_bf16(af[mb], bfv[nb], acc[mb][nb], 0, 0, 0);
        __syncthreads();
    }
    ushort_t* outp; int nc0;
    if (n0 < 768){ outp = xp; nc0 = n0; } else { outp = zz; nc0 = n0 - 768; }
    int rbase = (l >> 4) * 4, cl = l & 15;
    #pragma unroll
    for (int mb = 0; mb < 4; mb++)
        #pragma unroll
        for (int nb = 0; nb < 4; nb++){
            long row = m0 + wm*64 + mb*16 + rbase;
            int col = nc0 + wn*64 + nb*16 + cl;
            #pragma unroll
            for (int r = 0; r < 4; r++)
                outp[(row + r)*768 + col] = f2bf(acc[mb][nb][r]);
        }
}

// ---------------- k5: causal depthwise conv K=4 + SiLU ----------------
__global__ __launch_bounds__(256) void k_conv(char* ws){
    const ushort_t* xp = (const ushort_t*)(ws + O_XP);
    ushort_t* xc = (ushort_t*)(ws + O_XC);
    const float* cw = (const float*)(ws + O_CONVW);
    const float* cb = (const float*)(ws + O_CONVB);
    int d = blockIdx.x*256 + threadIdx.x;
    int t0 = blockIdx.y * 8;
    int b = blockIdx.z;
    long rbase = (long)b * L_;
    float w0 = cw[d*4], w1 = cw[d*4+1], w2 = cw[d*4+2], w3 = cw[d*4+3];
    float bias = cb[d];
    float xv[11];
    #pragma unroll
    for (int i = 0; i < 11; i++){
        int t = t0 - 3 + i;
        xv[i] = (t >= 0) ? bf2f(xp[(rbase + t)*768 + d]) : 0.f;
    }
    #pragma unroll
    for (int tt = 0; tt < 8; tt++){
        float v = bias + xv[tt]*w0 + xv[tt+1]*w1 + xv[tt+2]*w2 + xv[tt+3]*w3;
        v = v * sigm(v);
        xc[(rbase + t0 + tt)*768 + d] = f2bf(v);
    }
}

// ---------------- k6: xproj  xc[32768,768] @ W_xproj -> x_dbl[32768,56] ----
__global__ __launch_bounds__(256) void k_xproj(char* ws){
    const ushort_t* xc = (const ushort_t*)(ws + O_XC);
    const ushort_t* wT = (const ushort_t*)(ws + O_WXT);
    float* xdbl = (float*)(ws + O_XDBL);
    __shared__ ushort_t sA[128*32];
    __shared__ ushort_t sB[64*32];
    int tid = threadIdx.x, w = tid >> 6, l = tid & 63;
    long m0 = (long)blockIdx.x * 128;
    f32x4 acc[2][4] = {};
    int lr = l >> 2, lk = (l & 3) * 8;
    const ushort_t* gA = xc + (m0 + w*16 + lr)*768 + lk;
    const ushort_t* gB = wT + ((long)(w*16 + lr))*768 + lk;
    ushort_t* lA = &sA[w*16*32];
    ushort_t* lB = &sB[w*16*32];
    int arow0 = w*32 + (l & 15);
    int brow = l & 15;
    int koff = (l >> 4) * 8;
    for (int kc = 0; kc < 24; kc++){
        int k0 = kc * 32;
        gload_lds16(gA + k0,           lA);
        gload_lds16(gA + k0 + 64*768,  lA + 64*32);
        gload_lds16(gB + k0,           lB);
        __syncthreads();
        bf16x8 af[2], bfv[4];
        af[0] = *(const bf16x8*)&sA[arow0*32 + koff];
        af[1] = *(const bf16x8*)&sA[(arow0+16)*32 + koff];
        #pragma unroll
        for (int nb = 0; nb < 4; nb++)
            bfv[nb] = *(const bf16x8*)&sB[(nb*16 + brow)*32 + koff];
        #pragma unroll
        for (int mb = 0; mb < 2; mb++)
            #pragma unroll
            for (int nb = 0; nb < 4; nb++)
                acc[mb][nb] = __builtin_amdgcn_mfma_f32_16x16x32_bf16(af[mb], bfv[nb], acc[mb][nb], 0, 0, 0);
        __syncthreads();
    }
    int rbase = (l >> 4) * 4, cl = l & 15;
    #pragma unroll
    for (int mb = 0; mb < 2; mb++)
        #pragma unroll
        for (int nb = 0; nb < 4; nb++){
            int col = nb*16 + cl;
            if (col < 56){
                long row = m0 + w*32 + mb*16 + rbase;
                #pragma unroll
                for (int r = 0; r < 4; r++)
                    xdbl[(row + r)*56 + col] = acc[mb][nb][r];
            }
        }
}

// ---------------- k7: selective scan + fused dt + fused epilogue ----------
// lane = (s, dg): 16 states per (b,d), 8 d per 128-thread block.
// dt computed in-kernel from xdbl (no O_DT buffer, no dt HBM round-trip).
// ymean[b,d] = mean_t (y_t + xc*Dskip) * silu(z)
__global__ __launch_bounds__(128) void k_scan(char* ws){
    const ushort_t* xc = (const ushort_t*)(ws + O_XC);
    const ushort_t* zb = (const ushort_t*)(ws + O_Z);
    const float* xdbl = (const float*)(ws + O_XDBL);
    const float* A = (const float*)(ws + O_A);
    const float* Dsk = (const float*)(ws + O_DSKIP);
    const float* Wdt = (const float*)(ws + O_WDT);
    const float* dtb = (const float*)(ws + O_DTB);
    float* ymean = (float*)(ws + O_YMEAN);
    int d0 = blockIdx.x * 8;
    int b = blockIdx.y;
    int tid = threadIdx.x, dg = tid >> 4, s = tid & 15;
    int d = d0 + dg;
    float Av = A[d*16 + s];
    float Dv = Dsk[d];
    long base = (long)b * L_;
    // dt-compute role: thread handles (st_t, st_d)
    int st_t = tid >> 3, st_d = tid & 7;
    float wdt[24];
    #pragma unroll
    for (int k = 0; k < 24; k++) wdt[k] = Wdt[k*768 + d0 + st_d];
    float dbias = dtb[d0 + st_d];
    __shared__ float sXD[16*56];          // full xdbl rows: dt_r|B|C
    __shared__ float sDT[16*8], sXC[16*8], sZ[16*8];
    float h = 0.f, ysum = 0.f;
    for (int t0 = 0; t0 < L_; t0 += 16){
        long rb = base + t0;
        // xdbl rows are contiguous: 896 floats
        #pragma unroll
        for (int i = 0; i < 7; i++)
            sXD[tid + i*128] = xdbl[rb*56 + tid + i*128];
        long row = rb + st_t;
        sXC[st_t*8 + st_d] = bf2f(xc[row*768 + d0 + st_d]);
        sZ [st_t*8 + st_d] = bf2f(zb[row*768 + d0 + st_d]);
        __syncthreads();
        // dt = softplus(dt_r @ W_dt + bias), one (t,d) per thread
        float acc = dbias;
        #pragma unroll
        for (int k = 0; k < 24; k++) acc += sXD[st_t*56 + k] * wdt[k];
        acc = (acc > 20.f) ? acc : log1pf(__expf(acc));
        sDT[st_t*8 + st_d] = acc;
        __syncthreads();
        #pragma unroll
        for (int tt = 0; tt < 16; tt++){
            float dtv = sDT[tt*8 + dg];
            float xcv = sXC[tt*8 + dg];
            float zv  = sZ [tt*8 + dg];
            float Bv  = sXD[tt*56 + 24 + s];
            float Cv  = sXD[tt*56 + 40 + s];
            float dA = __expf(dtv * Av);
            h = dA*h + (dtv*xcv)*Bv;
            float yp = h * Cv;
            yp += __shfl_xor(yp, 1, 16);
            yp += __shfl_xor(yp, 2, 16);
            yp += __shfl_xor(yp, 4, 16);
            yp += __shfl_xor(yp, 8, 16);
            ysum += (yp + xcv*Dv) * (zv * sigm(zv));
        }
        __syncthreads();
    }
    if (s == 0) ymean[b*768 + d] = ysum * (1.f/L_);
}

// ---------------- k8: head part 1: pooled -> h = pooled@W_fc + b_fc ------
__global__ __launch_bounds__(256) void k_head1(char* ws){
    const float* ymean = (const float*)(ws + O_YMEAN);
    const float* xmean = (const float*)(ws + O_XMEAN);
    const float* Wout = (const float*)(ws + O_WOUT);
    const float* Wfc = (const float*)(ws + O_WFC);
    const float* bfc = (const float*)(ws + O_BFC);
    float* hbuf = (float*)(ws + O_H);
    int b = blockIdx.x, tid = threadIdx.x;
    __shared__ float sY[768];
    __shared__ float sP[384];
    sY[tid] = ymean[b*768 + tid];
    sY[tid+256] = ymean[b*768 + tid + 256];
    sY[tid+512] = ymean[b*768 + tid + 512];
    __syncthreads();
    for (int d = tid; d < 384; d += 256){
        float v = xmean[b*384 + d];
        for (int i = 0; i < 768; i++) v += sY[i] * Wout[i*384 + d];
        sP[d] = v;
    }
    __syncthreads();
    float v = bfc[tid];
    for (int dd = 0; dd < 384; dd++) v += sP[dd] * Wfc[dd*256 + tid];
    hbuf[b*256 + tid] = v;
}

// ---------------- k9: head part 2: batchnorm + relu + classifier --------
__global__ __launch_bounds__(384) void k_head2(char* ws, void* out){
    const int flag = *(const int*)(ws + O_FLAG);
    const float* hbuf = (const float*)(ws + O_H);
    const float* gam = (const float*)(ws + O_GAM);
    const float* bet = (const float*)(ws + O_BET);
    const float* Wcls = (const float*)(ws + O_WCLS);
    const float* bcls = (const float*)(ws + O_BCLS);
    int tid = threadIdx.x;
    __shared__ float sH[8*256];
    if (tid < 256){
        float hv[8]; float mu = 0.f;
        #pragma unroll
        for (int b = 0; b < 8; b++){ hv[b] = hbuf[b*256 + tid]; mu += hv[b]; }
        mu *= 0.125f;
        float var = 0.f;
        #pragma unroll
        for (int b = 0; b < 8; b++){ float dv = hv[b]-mu; var += dv*dv; }
        var *= 0.125f;
        float rs = rsqrtf(var + 1e-5f);
        #pragma unroll
        for (int b = 0; b < 8; b++){
            float t = (hv[b]-mu)*rs*gam[tid] + bet[tid];
            sH[b*256 + tid] = t > 0.f ? t : 0.f;
        }
    }
    __syncthreads();
    if (tid < 320){
        int b = tid / 40, c = tid % 40;
        float acc = bcls[c];
        for (int j = 0; j < 256; j++) acc += sH[b*256 + j] * Wcls[j*40 + c];
        if (flag) ((ushort_t*)out)[b*40 + c] = f2bf(acc);
        else      ((float*)out)[b*40 + c] = acc;
    }
}

// ---------------- launch ----------------
extern "C" void kernel_launch(void* const* d_in, const int* in_sizes, int n_in,
                              void* d_out, int out_size, void* d_ws, size_t ws_size,
                              hipStream_t stream){
    (void)in_sizes; (void)n_in; (void)out_size; (void)ws_size;
    char* ws = (char*)d_ws;
    Ptrs ps;
    for (int i = 0; i < 17; i++) ps.p[i] = d_in[i];

    k_detect<<<1, 256, 0, stream>>>(d_in[0], ws);
    k_prep<<<(unsigned)((N_PREP + 255) / 256), 256, 0, stream>>>(ps, ws);
    k_rmsnorm<<<ML_, 128, 0, stream>>>(d_in[0], ws);
    k_xmean<<<dim3(8, 3, 16), 256, 0, stream>>>(d_in[0], ws);
    k_gemm1<<<dim3(ML_/128, 12), 256, 0, stream>>>(ws);
    k_conv<<<dim3(3, L_/8, B_), 256, 0, stream>>>(ws);
    k_xproj<<<ML_/128, 256, 0, stream>>>(ws);
    k_scan<<<dim3(96, B_), 128, 0, stream>>>(ws);
    k_head1<<<B_, 256, 0, stream>>>(ws);
    k_head2<<<1, 384, 0, stream>>>(ws, d_out);
}